// Round 1
// baseline (174.221 us; speedup 1.0000x reference)
//
#include <hip/hip_runtime.h>
#include <hip/hip_bf16.h>
#include <stdint.h>

#define HEAD 64
#define CEMB 1024
#define BB 8
#define TSEQ 2048

typedef __attribute__((ext_vector_type(8))) short bf16x8;
typedef __attribute__((ext_vector_type(4))) float f32x4;

__device__ __forceinline__ unsigned short f2bf(float f) {
    union { float f; uint32_t u; } c; c.f = f;
    uint32_t u = c.u + 0x7FFF + ((c.u >> 16) & 1);
    return (unsigned short)(u >> 16);
}

// ---------------- Kernel 0: W -> WT bf16 [192][1024], scale folded into q ----
__global__ __launch_bounds__(256) void prep_w(
        const float* __restrict__ Wk, const float* __restrict__ bk,
        const float* __restrict__ Wq, const float* __restrict__ bq,
        const float* __restrict__ Wv, const float* __restrict__ bv,
        unsigned short* __restrict__ WT, float* __restrict__ biasb) {
    int n = blockIdx.x;               // 0..191
    int proj = n >> 6, col = n & 63;
    const float* W  = (proj == 0) ? Wk : (proj == 1) ? Wq : Wv;
    const float* bi = (proj == 0) ? bk : (proj == 1) ? bq : bv;
    float scale = (proj == 1) ? 0.03125f : 1.0f;   // C^-0.5 = 1/32 folded into q
    for (int k = threadIdx.x; k < CEMB; k += 256)
        WT[n * CEMB + k] = f2bf(W[k * HEAD + col] * scale);
    if (threadIdx.x == 0) biasb[n] = bi[col] * scale;
}

// ---------------- Kernel 1: projections  [16384 x 1024] @ [1024 x 192] -------
// outputs: Kb [b][t][64] bf16, Qb [b][t][64] bf16 (scaled), VTb [b][64][2048] bf16
__global__ __launch_bounds__(512) void proj_gemm(
        const float* __restrict__ x, const unsigned short* __restrict__ WT,
        const float* __restrict__ biasb,
        unsigned short* __restrict__ Kb, unsigned short* __restrict__ Qb,
        unsigned short* __restrict__ VTb) {
    __shared__ __align__(16) unsigned short As[64 * 40];   // [row][k] pad 40
    __shared__ __align__(16) unsigned short Bs[192 * 40];  // [n][k]   pad 40

    const int tid  = threadIdx.x;
    const int lane = tid & 63, w = tid >> 6;     // 8 waves
    const int l15  = lane & 15, q4 = lane >> 4;
    const int mw   = w & 1, nw = w >> 1;         // wave: 2 m-tiles x 3 n-tiles
    const long rowbase = (long)blockIdx.x * 64;

    f32x4 z = {0.f, 0.f, 0.f, 0.f};
    f32x4 acc[2][3];
    for (int a = 0; a < 2; a++) for (int b = 0; b < 3; b++) acc[a][b] = z;

    const int ar  = tid >> 3;        // staging row 0..63
    const int akq = tid & 7;         // 4 floats each
    const float* xg = x + (rowbase + ar) * CEMB + akq * 4;

    for (int k0 = 0; k0 < CEMB; k0 += 32) {
        // stage A: 64x32 fp32 -> bf16 LDS
        float4 av = *(const float4*)(xg + k0);
        ushort4 a4;
        a4.x = f2bf(av.x); a4.y = f2bf(av.y); a4.z = f2bf(av.z); a4.w = f2bf(av.w);
        *(ushort4*)(&As[ar * 40 + akq * 4]) = a4;
        // stage B: 192x32 bf16 copy (two rounds of 16B chunks)
        {
            int n = tid >> 2, kq = tid & 3;      // flat 0..511
            if (n < 192)
                *(int4*)(&Bs[n * 40 + kq * 8]) =
                    *(const int4*)(WT + (long)n * CEMB + k0 + kq * 8);
            if (tid < 256) {
                int n2 = 128 + (tid >> 2), kq2 = tid & 3;  // flat 512..767
                *(int4*)(&Bs[n2 * 40 + kq2 * 8]) =
                    *(const int4*)(WT + (long)n2 * CEMB + k0 + kq2 * 8);
            }
        }
        __syncthreads();
        bf16x8 afr[2], bfr[3];
        for (int mt = 0; mt < 2; mt++)
            afr[mt] = *(const bf16x8*)(&As[((mw * 2 + mt) * 16 + l15) * 40 + q4 * 8]);
        for (int j = 0; j < 3; j++)
            bfr[j] = *(const bf16x8*)(&Bs[((nw * 3 + j) * 16 + l15) * 40 + q4 * 8]);
        for (int mt = 0; mt < 2; mt++)
            for (int j = 0; j < 3; j++)
                acc[mt][j] = __builtin_amdgcn_mfma_f32_16x16x32_bf16(
                    afr[mt], bfr[j], acc[mt][j], 0, 0, 0);
        __syncthreads();
    }

    // epilogue: +bias, cast bf16, scatter to K / Q / VT
    for (int j = 0; j < 3; j++) {
        int n = nw * 48 + j * 16 + l15;
        float bias = biasb[n];
        for (int mt = 0; mt < 2; mt++) {
            long row0 = rowbase + (mw * 2 + mt) * 16 + q4 * 4;   // 4 consecutive rows
            if (n < 128) {
                unsigned short* dst = (n < 64) ? (Kb + row0 * HEAD + n)
                                               : (Qb + row0 * HEAD + (n - 64));
                for (int r = 0; r < 4; r++)
                    dst[r * HEAD] = f2bf(acc[mt][j][r] + bias);
            } else {
                int h = n - 128;
                long b = row0 >> 11; int t = (int)(row0 & 2047);
                ushort4 p;
                p.x = f2bf(acc[mt][j][0] + bias);
                p.y = f2bf(acc[mt][j][1] + bias);
                p.z = f2bf(acc[mt][j][2] + bias);
                p.w = f2bf(acc[mt][j][3] + bias);
                *(ushort4*)(VTb + b * (HEAD * (long)TSEQ) + (long)h * TSEQ + t) = p;
            }
        }
    }
}

// ---------------- Kernel 2: causal softplus-attention -----------------------
// block = (b, t-16-tile); 4 waves split s-chunks (32 s each) interleaved.
__global__ __launch_bounds__(256) void attn(
        const unsigned short* __restrict__ Kb, const unsigned short* __restrict__ Qb,
        const unsigned short* __restrict__ VTb, float* __restrict__ out) {
    __shared__ __align__(16) unsigned short Pl[4][16 * 40];  // per-wave [t=16][s pad 40]
    __shared__ __align__(16) float red[3][64 * 20];

    const int tid = threadIdx.x;
    const int lane = tid & 63, w = tid >> 6;
    const int l15 = lane & 15, q4 = lane >> 4;

    const int bid = blockIdx.x;                 // 0..1023
    const int ti = 127 - (bid >> 3);            // largest t first (load balance)
    const int b = bid & 7;
    const int t0 = ti * 16;

    const unsigned short* kb  = Kb  + (long)b * TSEQ * HEAD;
    const unsigned short* qb  = Qb  + (long)b * TSEQ * HEAD;
    const unsigned short* vtb = VTb + (long)b * HEAD * TSEQ;

    // K fragments for this t-tile (fixed): B-operand, n = t-local, k = h
    bf16x8 kf0 = *(const bf16x8*)(kb + (t0 + l15) * HEAD + q4 * 8);
    bf16x8 kf1 = *(const bf16x8*)(kb + (t0 + l15) * HEAD + 32 + q4 * 8);

    f32x4 z = {0.f, 0.f, 0.f, 0.f};
    f32x4 oacc[4] = {z, z, z, z};               // O^T: 4 h-tiles x (16h x 16t)

    unsigned short* myP = &Pl[w][0];
    const int nchunk = (t0 + 15) / 32 + 1;

    for (int c = w; c < nchunk; c += 4) {
        const int s0 = c * 32;
        // S^T = Q K^T, two 16x16 tiles (s-local 0..15 / 16..31)
        f32x4 st[2];
        for (int tile = 0; tile < 2; tile++) {
            int sb = s0 + tile * 16;
            bf16x8 qf0 = *(const bf16x8*)(qb + (sb + l15) * HEAD + q4 * 8);
            bf16x8 qf1 = *(const bf16x8*)(qb + (sb + l15) * HEAD + 32 + q4 * 8);
            f32x4 sc = z;
            sc = __builtin_amdgcn_mfma_f32_16x16x32_bf16(qf0, kf0, sc, 0, 0, 0);
            sc = __builtin_amdgcn_mfma_f32_16x16x32_bf16(qf1, kf1, sc, 0, 0, 0);
            st[tile] = sc;
        }
        // softplus + causal mask, pack bf16, store to per-wave LDS [t][s]
        const int tg = t0 + l15;
        for (int tile = 0; tile < 2; tile++) {
            ushort4 pk;
            unsigned short pv[4];
            for (int r = 0; r < 4; r++) {
                int sg = s0 + tile * 16 + q4 * 4 + r;
                float p = __logf(1.0f + __expf(st[tile][r]));
                if (sg > tg) p = 0.0f;
                pv[r] = f2bf(p);
            }
            pk.x = pv[0]; pk.y = pv[1]; pk.z = pv[2]; pk.w = pv[3];
            *(ushort4*)(myP + l15 * 40 + tile * 16 + q4 * 4) = pk;
        }
        __threadfence_block();   // order LDS write -> cross-lane LDS read (same wave)
        // P^T as B-operand: k = s-local = q4*8+j, n = t-local = l15
        bf16x8 pf = *(const bf16x8*)(myP + l15 * 40 + q4 * 8);
        // O^T += V^T @ P^T over 4 h-tiles
        for (int hh = 0; hh < 4; hh++) {
            bf16x8 vf = *(const bf16x8*)(vtb + (hh * 16 + l15) * (long)TSEQ + s0 + q4 * 8);
            oacc[hh] = __builtin_amdgcn_mfma_f32_16x16x32_bf16(vf, pf, oacc[hh], 0, 0, 0);
        }
    }

    // cross-wave reduction of O^T partials
    if (w > 0) {
        float* r0 = &red[w - 1][lane * 20];
        for (int hh = 0; hh < 4; hh++)
            *(f32x4*)(r0 + hh * 4) = oacc[hh];
    }
    __syncthreads();
    if (w == 0) {
        for (int i = 0; i < 3; i++) {
            const float* r0 = &red[i][lane * 20];
            for (int hh = 0; hh < 4; hh++)
                oacc[hh] += *(const f32x4*)(r0 + hh * 4);
        }
        // out[b][t][h]: t = t0 + l15, h = hh*16 + q4*4 + r  -> float4 stores
        float* ob = out + ((long)b * TSEQ + t0 + l15) * HEAD + q4 * 4;
        for (int hh = 0; hh < 4; hh++)
            *(f32x4*)(ob + hh * 16) = oacc[hh];
    }
}

// ---------------- host launch ------------------------------------------------
extern "C" void kernel_launch(void* const* d_in, const int* in_sizes, int n_in,
                              void* d_out, int out_size, void* d_ws, size_t ws_size,
                              hipStream_t stream) {
    const float* x  = (const float*)d_in[0];
    const float* Wk = (const float*)d_in[1];
    const float* bk = (const float*)d_in[2];
    const float* Wq = (const float*)d_in[3];
    const float* bq = (const float*)d_in[4];
    const float* Wv = (const float*)d_in[5];
    const float* bv = (const float*)d_in[6];
    float* out = (float*)d_out;

    char* ws = (char*)d_ws;
    unsigned short* WT    = (unsigned short*)(ws);                      // 384 KB
    float*          biasb = (float*)(ws + 393216);                      // 768 B
    unsigned short* Kb    = (unsigned short*)(ws + 524288);             // 2 MB
    unsigned short* Qb    = (unsigned short*)(ws + 524288 + 2097152);   // 2 MB
    unsigned short* VTb   = (unsigned short*)(ws + 524288 + 4194304);   // 2 MB

    prep_w<<<192, 256, 0, stream>>>(Wk, bk, Wq, bq, Wv, bv, WT, biasb);
    proj_gemm<<<256, 512, 0, stream>>>(x, WT, biasb, Kb, Qb, VTb);
    attn<<<1024, 256, 0, stream>>>(Kb, Qb, VTb, out);
}

// Round 2
// 163.855 us; speedup vs baseline: 1.0633x; 1.0633x over previous
//
#include <hip/hip_runtime.h>
#include <hip/hip_bf16.h>
#include <stdint.h>

#define HEAD 64
#define CEMB 1024
#define BB 8
#define TSEQ 2048
#define PBK 64

typedef __attribute__((ext_vector_type(8))) short bf16x8;
typedef __attribute__((ext_vector_type(4))) float f32x4;

__device__ __forceinline__ unsigned short f2bf(float f) {
    union { float f; uint32_t u; } c; c.f = f;
    uint32_t u = c.u + 0x7FFF + ((c.u >> 16) & 1);
    return (unsigned short)(u >> 16);
}

// ---------------- Kernel 0: W -> WT bf16 [192][1024] via LDS transpose -------
// grid 48: p = blk>>4 (proj), kc = blk&15 (64-k chunk). Coalesced load + store.
__global__ __launch_bounds__(256) void prep_w(
        const float* __restrict__ Wk, const float* __restrict__ bk,
        const float* __restrict__ Wq, const float* __restrict__ bq,
        const float* __restrict__ Wv, const float* __restrict__ bv,
        unsigned short* __restrict__ WT, float* __restrict__ biasb) {
    __shared__ float Ws[64][68];
    const int p = blockIdx.x >> 4, kc = blockIdx.x & 15;
    const float* W  = (p == 0) ? Wk : (p == 1) ? Wq : Wv;
    const float* bi = (p == 0) ? bk : (p == 1) ? bq : bv;
    const float scale = (p == 1) ? 0.03125f : 1.0f;   // fold C^-0.5 into q
    const int tid = threadIdx.x;
    const int h4 = (tid & 15) * 4;
    for (int r = 0; r < 4; r++) {
        int kl = (tid >> 4) + r * 16;
        float4 v = *(const float4*)(W + (long)(kc * 64 + kl) * 64 + h4);
        *(float4*)(&Ws[kl][h4]) = v;
    }
    __syncthreads();
    const int h = tid >> 2, k0 = (tid & 3) * 16;
    unsigned short ov[16];
    for (int i = 0; i < 16; i++) ov[i] = f2bf(Ws[k0 + i][h] * scale);
    unsigned short* dst = WT + (long)(p * 64 + h) * CEMB + kc * 64 + k0;
    *(int4*)(dst)     = *(int4*)(ov);
    *(int4*)(dst + 8) = *((int4*)(ov) + 1);
    if (kc == 0 && tid < 64) biasb[p * 64 + tid] = bi[tid] * scale;
}

// ---------------- Kernel 1: projections  [16384 x 1024] @ [1024 x 192] -------
// grid 512, 256 thr (4 waves). Block = 32 rows. Wave: 16 rows x 96 cols.
// A: global->reg prefetch (1 seg ahead). B: LDS double-buffer, 1 barrier/seg.
__global__ __launch_bounds__(256) void proj_gemm(
        const float* __restrict__ x, const unsigned short* __restrict__ WT,
        const float* __restrict__ biasb,
        unsigned short* __restrict__ Kb, unsigned short* __restrict__ Qb,
        unsigned short* __restrict__ VTb) {
    __shared__ __align__(16) unsigned short Bs[2][192 * 72];  // stride 72 bf16

    const int tid = threadIdx.x;
    const int lane = tid & 63, w = tid >> 6;
    const int l15 = lane & 15, q4 = lane >> 4;
    const int mw = w & 1, nw = w >> 1;            // 2 m-tiles x 2 n-halves
    const long rowbase = (long)blockIdx.x * 32;

    const float* xg = x + (rowbase + mw * 16 + l15) * CEMB + q4 * 8;

    f32x4 z = {0.f, 0.f, 0.f, 0.f};
    f32x4 acc[6];
    for (int j = 0; j < 6; j++) acc[j] = z;

    float4 apf[4];
    int4   bpf[6];

    // prefetch + stage segment 0
    for (int kk = 0; kk < 2; kk++)
        for (int c = 0; c < 2; c++)
            apf[kk * 2 + c] = *(const float4*)(xg + kk * 32 + c * 4);
    for (int i = 0; i < 6; i++) {
        int c = i * 256 + tid, n = c >> 3, kc = c & 7;
        bpf[i] = *(const int4*)(WT + (long)n * CEMB + kc * 8);
    }
    for (int i = 0; i < 6; i++) {
        int c = i * 256 + tid, n = c >> 3, kc = c & 7;
        *(int4*)(&Bs[0][n * 72 + kc * 8]) = bpf[i];
    }
    __syncthreads();

    for (int seg = 0; seg < 16; seg++) {
        const int cur = seg & 1;
        // extract current A into bf16 fragments (before prefetch clobbers apf)
        bf16x8 af[2];
        for (int kk = 0; kk < 2; kk++) {
            unsigned short t8[8];
            const float* f = (const float*)&apf[kk * 2];
            for (int e = 0; e < 8; e++) t8[e] = f2bf(f[e]);
            af[kk] = *(bf16x8*)t8;
        }
        // issue next-segment global loads (stay in flight across MFMA)
        if (seg < 15) {
            const float* xs = xg + (seg + 1) * PBK;
            for (int kk = 0; kk < 2; kk++)
                for (int c = 0; c < 2; c++)
                    apf[kk * 2 + c] = *(const float4*)(xs + kk * 32 + c * 4);
            for (int i = 0; i < 6; i++) {
                int c = i * 256 + tid, n = c >> 3, kc = c & 7;
                bpf[i] = *(const int4*)(WT + (long)n * CEMB + (seg + 1) * PBK + kc * 8);
            }
        }
        // compute on Bs[cur]
        for (int kk = 0; kk < 2; kk++)
            for (int j = 0; j < 6; j++) {
                bf16x8 bf = *(const bf16x8*)(
                    &Bs[cur][(nw * 96 + j * 16 + l15) * 72 + kk * 32 + q4 * 8]);
                acc[j] = __builtin_amdgcn_mfma_f32_16x16x32_bf16(af[kk], bf, acc[j], 0, 0, 0);
            }
        // stage next segment into the other buffer (safe: everyone finished
        // reading it at the END of seg-1's barrier), then single barrier.
        if (seg < 15) {
            for (int i = 0; i < 6; i++) {
                int c = i * 256 + tid, n = c >> 3, kc = c & 7;
                *(int4*)(&Bs[cur ^ 1][n * 72 + kc * 8]) = bpf[i];
            }
        }
        __syncthreads();
    }

    // epilogue: +bias, cast bf16, scatter to K / Q / VT
    for (int j = 0; j < 6; j++) {
        const int n = nw * 96 + j * 16 + l15;
        const float bias = biasb[n];
        const long row0 = rowbase + mw * 16 + q4 * 4;
        if (n < 128) {
            unsigned short* dst = (n < 64) ? (Kb + row0 * HEAD + n)
                                           : (Qb + row0 * HEAD + (n - 64));
            for (int r = 0; r < 4; r++)
                dst[r * HEAD] = f2bf(acc[j][r] + bias);
        } else {
            const int h = n - 128;
            const long b = row0 >> 11; const int t = (int)(row0 & 2047);
            ushort4 pk;
            pk.x = f2bf(acc[j][0] + bias);
            pk.y = f2bf(acc[j][1] + bias);
            pk.z = f2bf(acc[j][2] + bias);
            pk.w = f2bf(acc[j][3] + bias);
            *(ushort4*)(VTb + b * (HEAD * (long)TSEQ) + (long)h * TSEQ + t) = pk;
        }
    }
}

// ---------------- Kernel 2: causal softplus-attention (unchanged) ------------
__global__ __launch_bounds__(256) void attn(
        const unsigned short* __restrict__ Kb, const unsigned short* __restrict__ Qb,
        const unsigned short* __restrict__ VTb, float* __restrict__ out) {
    __shared__ __align__(16) unsigned short Pl[4][16 * 40];
    __shared__ __align__(16) float red[3][64 * 20];

    const int tid = threadIdx.x;
    const int lane = tid & 63, w = tid >> 6;
    const int l15 = lane & 15, q4 = lane >> 4;

    const int bid = blockIdx.x;
    const int ti = 127 - (bid >> 3);
    const int b = bid & 7;
    const int t0 = ti * 16;

    const unsigned short* kb  = Kb  + (long)b * TSEQ * HEAD;
    const unsigned short* qb  = Qb  + (long)b * TSEQ * HEAD;
    const unsigned short* vtb = VTb + (long)b * HEAD * TSEQ;

    bf16x8 kf0 = *(const bf16x8*)(kb + (t0 + l15) * HEAD + q4 * 8);
    bf16x8 kf1 = *(const bf16x8*)(kb + (t0 + l15) * HEAD + 32 + q4 * 8);

    f32x4 z = {0.f, 0.f, 0.f, 0.f};
    f32x4 oacc[4] = {z, z, z, z};

    unsigned short* myP = &Pl[w][0];
    const int nchunk = (t0 + 15) / 32 + 1;

    for (int c = w; c < nchunk; c += 4) {
        const int s0 = c * 32;
        f32x4 st[2];
        for (int tile = 0; tile < 2; tile++) {
            int sb = s0 + tile * 16;
            bf16x8 qf0 = *(const bf16x8*)(qb + (sb + l15) * HEAD + q4 * 8);
            bf16x8 qf1 = *(const bf16x8*)(qb + (sb + l15) * HEAD + 32 + q4 * 8);
            f32x4 sc = z;
            sc = __builtin_amdgcn_mfma_f32_16x16x32_bf16(qf0, kf0, sc, 0, 0, 0);
            sc = __builtin_amdgcn_mfma_f32_16x16x32_bf16(qf1, kf1, sc, 0, 0, 0);
            st[tile] = sc;
        }
        const int tg = t0 + l15;
        for (int tile = 0; tile < 2; tile++) {
            ushort4 pk;
            unsigned short pv[4];
            for (int r = 0; r < 4; r++) {
                int sg = s0 + tile * 16 + q4 * 4 + r;
                float p = __logf(1.0f + __expf(st[tile][r]));
                if (sg > tg) p = 0.0f;
                pv[r] = f2bf(p);
            }
            pk.x = pv[0]; pk.y = pv[1]; pk.z = pv[2]; pk.w = pv[3];
            *(ushort4*)(myP + l15 * 40 + tile * 16 + q4 * 4) = pk;
        }
        __threadfence_block();
        bf16x8 pf = *(const bf16x8*)(myP + l15 * 40 + q4 * 8);
        for (int hh = 0; hh < 4; hh++) {
            bf16x8 vf = *(const bf16x8*)(vtb + (hh * 16 + l15) * (long)TSEQ + s0 + q4 * 8);
            oacc[hh] = __builtin_amdgcn_mfma_f32_16x16x32_bf16(vf, pf, oacc[hh], 0, 0, 0);
        }
    }

    if (w > 0) {
        float* r0 = &red[w - 1][lane * 20];
        for (int hh = 0; hh < 4; hh++)
            *(f32x4*)(r0 + hh * 4) = oacc[hh];
    }
    __syncthreads();
    if (w == 0) {
        for (int i = 0; i < 3; i++) {
            const float* r0 = &red[i][lane * 20];
            for (int hh = 0; hh < 4; hh++)
                oacc[hh] += *(const f32x4*)(r0 + hh * 4);
        }
        float* ob = out + ((long)b * TSEQ + t0 + l15) * HEAD + q4 * 4;
        for (int hh = 0; hh < 4; hh++)
            *(f32x4*)(ob + hh * 16) = oacc[hh];
    }
}

// ---------------- host launch ------------------------------------------------
extern "C" void kernel_launch(void* const* d_in, const int* in_sizes, int n_in,
                              void* d_out, int out_size, void* d_ws, size_t ws_size,
                              hipStream_t stream) {
    const float* x  = (const float*)d_in[0];
    const float* Wk = (const float*)d_in[1];
    const float* bk = (const float*)d_in[2];
    const float* Wq = (const float*)d_in[3];
    const float* bq = (const float*)d_in[4];
    const float* Wv = (const float*)d_in[5];
    const float* bv = (const float*)d_in[6];
    float* out = (float*)d_out;

    char* ws = (char*)d_ws;
    unsigned short* WT    = (unsigned short*)(ws);                      // 384 KB
    float*          biasb = (float*)(ws + 393216);                      // 768 B
    unsigned short* Kb    = (unsigned short*)(ws + 524288);             // 2 MB
    unsigned short* Qb    = (unsigned short*)(ws + 524288 + 2097152);   // 2 MB
    unsigned short* VTb   = (unsigned short*)(ws + 524288 + 4194304);   // 2 MB

    prep_w<<<48, 256, 0, stream>>>(Wk, bk, Wq, bq, Wv, bv, WT, biasb);
    proj_gemm<<<512, 256, 0, stream>>>(x, WT, biasb, Kb, Qb, VTb);
    attn<<<1024, 256, 0, stream>>>(Kb, Qb, VTb, out);
}